// Round 4
// baseline (118.005 us; speedup 1.0000x reference)
//
#include <hip/hip_runtime.h>

// AnnularDilatedKNN: B=4, N=4096, C=64, SAMPLE=16, DILATED_RATE=2, r^2=256.
// Round 4: amortize candidate loads 4x — each wave queries 4 points at once.
//  - block = 256 thr = 4 waves = 16 consecutive points; candidate chunk loaded
//    once per wave per 64 candidates, tested against 4 query points.
//  - bookkeeping (ballot mask, cnt, hit0) is wave-uniform -> SGPRs; hit0 via
//    scalar ctz on the first nonzero mask (no shuffle reduction).
//  - gather phase: round-1 proven coalesced layout (thread t <-> row (i,k)=t).
// Numerics bit-match numpy: contract off, sq=(x*x+y*y)+z*z,
// dot=(xi*xj+yi*yj)+zi*zj, d2=(sqi+sqj)-2*dot.

#define BB 4
#define NN 4096
#define KK 16
#define NPB 16                  // points per block
#define PLANE (NN * KK)         // 65536

// ---------- K1: P[b*N+j] = (x, y, z, sq) ----------
__global__ __launch_bounds__(256)
void build_soa(const float* __restrict__ xyz, float4* __restrict__ P)
{
#pragma clang fp contract(off)
    const int g = blockIdx.x * 256 + threadIdx.x;      // 0..16383
    const float x = xyz[3 * g], y = xyz[3 * g + 1], z = xyz[3 * g + 2];
    const float sq = (x * x + y * y) + z * z;
    P[g] = make_float4(x, y, z, sq);
}

// ---------- K2: fused ball query (4 pts/wave) + gather ----------
__global__ __launch_bounds__(256)
void query_gather(const float4* __restrict__ P, const float* __restrict__ feat,
                  float* __restrict__ out)
{
#pragma clang fp contract(off)
    __shared__ int sids[NPB * KK];

    const int beta = blockIdx.x;            // 0..1023
    const int b    = beta >> 8;             // 256 blocks per batch
    const int i0   = (beta & 255) * NPB;    // first point (in batch) of block
    const int t    = threadIdx.x;
    const int lane = t & 63;
    const int wave = t >> 6;

    const float4* Pb = P + (b << 12);

    // ---- query phase: wave handles points i0 + 4*wave + {0,1,2,3} ----
    {
        const int pl0 = wave * 4;
        const float4 pi0 = Pb[i0 + pl0 + 0];
        const float4 pi1 = Pb[i0 + pl0 + 1];
        const float4 pi2 = Pb[i0 + pl0 + 2];
        const float4 pi3 = Pb[i0 + pl0 + 3];
        const unsigned long long lt = (1ULL << lane) - 1ULL;
        int cnt0 = 0, cnt1 = 0, cnt2 = 0, cnt3 = 0;   // wave-uniform (SGPR)
        int h00 = 0, h01 = 0, h02 = 0, h03 = 0;       // first-hit j per point
        int* row0 = sids + (pl0 + 0) * KK;
        int* row1 = sids + (pl0 + 1) * KK;
        int* row2 = sids + (pl0 + 2) * KK;
        int* row3 = sids + (pl0 + 3) * KK;

        for (int jc = 0; jc < NN / 64; ++jc) {
            const int j = (jc << 6) + lane;
            const float4 pj = Pb[j];

            const float dot0 = (pi0.x * pj.x + pi0.y * pj.y) + pi0.z * pj.z;
            const float d20  = (pi0.w + pj.w) - 2.0f * dot0;
            const float dot1 = (pi1.x * pj.x + pi1.y * pj.y) + pi1.z * pj.z;
            const float d21  = (pi1.w + pj.w) - 2.0f * dot1;
            const float dot2 = (pi2.x * pj.x + pi2.y * pj.y) + pi2.z * pj.z;
            const float d22  = (pi2.w + pj.w) - 2.0f * dot2;
            const float dot3 = (pi3.x * pj.x + pi3.y * pj.y) + pi3.z * pj.z;
            const float d23  = (pi3.w + pj.w) - 2.0f * dot3;

            const bool hq0 = d20 < 256.0f;
            const bool hq1 = d21 < 256.0f;
            const bool hq2 = d22 < 256.0f;
            const bool hq3 = d23 < 256.0f;
            const unsigned long long m0 = __ballot(hq0);
            const unsigned long long m1 = __ballot(hq1);
            const unsigned long long m2 = __ballot(hq2);
            const unsigned long long m3 = __ballot(hq3);

            if (m0 | m1 | m2 | m3) {
                if (m0) {
                    if (cnt0 == 0) h00 = (jc << 6) + (int)__builtin_ctzll(m0);
                    const int r = cnt0 + __popcll(m0 & lt);
                    if (hq0 && r >= 16 && r <= 30) row0[r - 15] = j;
                    cnt0 += __popcll(m0);
                }
                if (m1) {
                    if (cnt1 == 0) h01 = (jc << 6) + (int)__builtin_ctzll(m1);
                    const int r = cnt1 + __popcll(m1 & lt);
                    if (hq1 && r >= 16 && r <= 30) row1[r - 15] = j;
                    cnt1 += __popcll(m1);
                }
                if (m2) {
                    if (cnt2 == 0) h02 = (jc << 6) + (int)__builtin_ctzll(m2);
                    const int r = cnt2 + __popcll(m2 & lt);
                    if (hq2 && r >= 16 && r <= 30) row2[r - 15] = j;
                    cnt2 += __popcll(m2);
                }
                if (m3) {
                    if (cnt3 == 0) h03 = (jc << 6) + (int)__builtin_ctzll(m3);
                    const int r = cnt3 + __popcll(m3 & lt);
                    if (hq3 && r >= 16 && r <= 30) row3[r - 15] = j;
                    cnt3 += __popcll(m3);
                }
                if (cnt0 >= 31 && cnt1 >= 31 && cnt2 >= 31 && cnt3 >= 31) break;
            }
        }

        // slot 0 + padding (slots above the last recorded rank) <- first hit
        if (lane < KK) {
            int hi;
            hi = (cnt0 < 31 ? cnt0 : 31) - 16;
            if (lane == 0 || lane > hi) row0[lane] = h00;
            hi = (cnt1 < 31 ? cnt1 : 31) - 16;
            if (lane == 0 || lane > hi) row1[lane] = h01;
            hi = (cnt2 < 31 ? cnt2 : 31) - 16;
            if (lane == 0 || lane > hi) row2[lane] = h02;
            hi = (cnt3 < 31 ? cnt3 : 31) - 16;
            if (lane == 0 || lane > hi) row3[lane] = h03;
        }
    }
    __syncthreads();

    // ---- gather phase: thread t owns output row (i,k) = t ----
    const int id = sids[t];
    const int ob = i0 * KK + t;             // offset inside each [N*K] plane

    const float4 p = Pb[id];
    float* o0 = out + (size_t)b * 3 * PLANE + ob;
    o0[0]         = p.x;
    o0[PLANE]     = p.y;
    o0[2 * PLANE] = p.z;

    const float4* frow = reinterpret_cast<const float4*>(feat + ((size_t)(b << 12) + id) * 64);
    float* o1 = out + (size_t)BB * 3 * PLANE + (size_t)b * 64 * PLANE + ob;
#pragma unroll
    for (int q = 0; q < 16; ++q) {
        const float4 v = frow[q];
        float* oc = o1 + (size_t)(4 * q) * PLANE;
        oc[0]         = v.x;
        oc[PLANE]     = v.y;
        oc[2 * PLANE] = v.z;
        oc[3 * PLANE] = v.w;
    }
}

extern "C" void kernel_launch(void* const* d_in, const int* in_sizes, int n_in,
                              void* d_out, int out_size, void* d_ws, size_t ws_size,
                              hipStream_t stream) {
    const float* xyz  = (const float*)d_in[0];
    const float* feat = (const float*)d_in[1];
    float* out = (float*)d_out;

    float4* P = (float4*)d_ws;                      // 16384 * 16 B = 256 KB

    build_soa   <<<BB * NN / 256, 256, 0, stream>>>(xyz, P);
    query_gather<<<BB * NN / NPB, 256, 0, stream>>>(P, feat, out);   // 1024 blocks
}